// Round 6
// baseline (3495.052 us; speedup 1.0000x reference)
//
#include <hip/hip_runtime.h>

typedef unsigned char u8;
typedef unsigned int u32;

#define T_STEPS 4
#define B_SZ 8
#define C_IN 512
#define CH 2048
#define N_SP 1024
#define S_C ((size_t)B_SZ * C_IN * N_SP)    // elems per timestep

// ---------------------------------------------------------------------------
// lif_x: x [T,B,C,N] fp32 -> xs u8 spikes, same flat layout (round-2 verbatim).
// ---------------------------------------------------------------------------
__global__ __launch_bounds__(256) void lif_x_kernel(const float* __restrict__ in,
                                                    u8* __restrict__ out)
{
    size_t i = (size_t)blockIdx.x * 256 + threadIdx.x;
    float v = 0.0f;
    #pragma unroll
    for (int t = 0; t < T_STEPS; ++t) {
        float x = in[(size_t)t * S_C + i];
        v += (x - v) * 0.5f;
        u8 s = (v >= 0.5f) ? 1 : 0;
        out[(size_t)t * S_C + i] = s;
        v = s ? 0.0f : v;
    }
}

// ---------------------------------------------------------------------------
// Fused GEMM + BN (+bias) + LIF, fp32, ascending-k single-accumulator per
// output => bit-identical to the round-2 passing kernel's math.
// Layouts: X [TB][K][N], W [CO][K] fp32, Y [TB][CO][N].
// MODE 0: LIF -> u8 spikes. MODE 1: y + res -> f32. MODE 2: LIF spike + in-place res -> f32.
// BSRC 0: u8 X. BSRC 1: u8 X * kvsf[k] (proj mask). BSRC 2: f32 X (fc1).
// F3: blockIdx.y selects among 3 fused problems (q/k/v share X).
// Tile 64co x 128n, 256 threads, per-thread 4co x 8n, t-loop outer.
// W broadcast via LDS; X straight from global (L1/L2-resident).
// ---------------------------------------------------------------------------
template<int MODE, int BSRC, bool BIAS, int K, int CO, bool F3>
__global__ __launch_bounds__(256) void mm(
    const float* __restrict__ W0, const float* __restrict__ W1, const float* __restrict__ W2,
    const void* __restrict__ Xv,
    const float* __restrict__ bn0, const float* __restrict__ bn1, const float* __restrict__ bn2,
    const float* __restrict__ bias,
    const float* __restrict__ kvsf,
    const float* __restrict__ res,
    void* Y0, void* Y1, void* Y2)
{
    __shared__ float Ws[32][64];
    const int b = blockIdx.z;
    int sel = 0, cb = blockIdx.y;
    if (F3) { sel = blockIdx.y >> 3; cb = blockIdx.y & 7; }
    const float* W   = (!F3 || sel == 0) ? W0  : (sel == 1 ? W1  : W2);
    const float* bnp = (!F3 || sel == 0) ? bn0 : (sel == 1 ? bn1 : bn2);
    void* Yv         = (!F3 || sel == 0) ? Y0  : (sel == 1 ? Y1  : Y2);

    const int coBase = cb * 64;
    const int nBase = blockIdx.x * 128;
    const int tid = threadIdx.x;
    const int tx = tid & 15, ty = tid >> 4;
    const int n0 = nBase + tx * 8;
    const int wco = tid & 63, wk = (tid >> 6) * 8;

    // BN constants (round-2 expressions)
    float scale[4], shift[4];
    #pragma unroll
    for (int i = 0; i < 4; ++i) {
        const int co = coBase + ty * 4 + i;
        const float g = bnp[co], be = bnp[CO + co];
        const float mn = bnp[2 * CO + co], vr = bnp[3 * CO + co];
        scale[i] = g / sqrtf(vr + 1e-5f);
        shift[i] = be - mn * scale[i];
        if (BIAS) shift[i] += bias[co] * scale[i];
    }

    float vst[4][8];
    if (MODE != 1) {
        #pragma unroll
        for (int i = 0; i < 4; ++i)
            #pragma unroll
            for (int j = 0; j < 8; ++j) vst[i][j] = 0.0f;
    }

    for (int t = 0; t < T_STEPS; ++t) {
        const int tb = t * B_SZ + b;
        const u8* Xu = (const u8*)Xv + (size_t)tb * K * N_SP;
        const float* Xf = (const float*)Xv + (size_t)tb * K * N_SP;
        float acc[4][8];
        #pragma unroll
        for (int i = 0; i < 4; ++i)
            #pragma unroll
            for (int j = 0; j < 8; ++j) acc[i][j] = 0.0f;

        for (int k0 = 0; k0 < K; k0 += 32) {
            __syncthreads();
            {   // stage W tile [32k][64co]
                const float* wp = W + (size_t)(coBase + wco) * K + k0 + wk;
                float4 w0 = *reinterpret_cast<const float4*>(wp);
                float4 w1 = *reinterpret_cast<const float4*>(wp + 4);
                Ws[wk + 0][wco] = w0.x; Ws[wk + 1][wco] = w0.y;
                Ws[wk + 2][wco] = w0.z; Ws[wk + 3][wco] = w0.w;
                Ws[wk + 4][wco] = w1.x; Ws[wk + 5][wco] = w1.y;
                Ws[wk + 6][wco] = w1.z; Ws[wk + 7][wco] = w1.w;
            }
            __syncthreads();

            if (BSRC <= 1) {
                #pragma unroll
                for (int h = 0; h < 2; ++h) {
                    uint2 xu[16];
                    #pragma unroll
                    for (int q = 0; q < 16; ++q)
                        xu[q] = *reinterpret_cast<const uint2*>(
                            Xu + (size_t)(k0 + h * 16 + q) * N_SP + n0);
                    #pragma unroll
                    for (int q = 0; q < 16; ++q) {
                        const int kk = h * 16 + q;
                        float4 wf = *reinterpret_cast<const float4*>(&Ws[kk][ty * 4]);
                        float wa[4] = {wf.x, wf.y, wf.z, wf.w};
                        float xf[8];
                        xf[0] = (float)( xu[q].x        & 0xFFu);
                        xf[1] = (float)((xu[q].x >> 8 ) & 0xFFu);
                        xf[2] = (float)((xu[q].x >> 16) & 0xFFu);
                        xf[3] = (float)( xu[q].x >> 24        );
                        xf[4] = (float)( xu[q].y        & 0xFFu);
                        xf[5] = (float)((xu[q].y >> 8 ) & 0xFFu);
                        xf[6] = (float)((xu[q].y >> 16) & 0xFFu);
                        xf[7] = (float)( xu[q].y >> 24        );
                        if (BSRC == 1) {
                            const float m = kvsf[(size_t)tb * K + k0 + kk];
                            #pragma unroll
                            for (int j = 0; j < 8; ++j) xf[j] *= m;
                        }
                        #pragma unroll
                        for (int i = 0; i < 4; ++i)
                            #pragma unroll
                            for (int j = 0; j < 8; ++j)
                                acc[i][j] += wa[i] * xf[j];
                    }
                }
            } else {
                #pragma unroll
                for (int h = 0; h < 8; ++h) {
                    float4 xa[4][2];
                    #pragma unroll
                    for (int q = 0; q < 4; ++q) {
                        const float* xp = Xf + (size_t)(k0 + h * 4 + q) * N_SP + n0;
                        xa[q][0] = *reinterpret_cast<const float4*>(xp);
                        xa[q][1] = *reinterpret_cast<const float4*>(xp + 4);
                    }
                    #pragma unroll
                    for (int q = 0; q < 4; ++q) {
                        const int kk = h * 4 + q;
                        float4 wf = *reinterpret_cast<const float4*>(&Ws[kk][ty * 4]);
                        float wa[4] = {wf.x, wf.y, wf.z, wf.w};
                        float xf[8] = {xa[q][0].x, xa[q][0].y, xa[q][0].z, xa[q][0].w,
                                       xa[q][1].x, xa[q][1].y, xa[q][1].z, xa[q][1].w};
                        #pragma unroll
                        for (int i = 0; i < 4; ++i)
                            #pragma unroll
                            for (int j = 0; j < 8; ++j)
                                acc[i][j] += wa[i] * xf[j];
                    }
                }
            }
        }

        // epilogue for this timestep (round-2 expressions)
        #pragma unroll
        for (int i = 0; i < 4; ++i) {
            const int co = coBase + ty * 4 + i;
            const size_t rowoff = ((size_t)tb * CO + co) * N_SP + n0;
            if (MODE == 0) {
                u32 p0 = 0, p1 = 0;
                #pragma unroll
                for (int j = 0; j < 8; ++j) {
                    const float y = acc[i][j] * scale[i] + shift[i];
                    float v = vst[i][j];
                    v += (y - v) * 0.5f;
                    const u32 s = (v >= 0.5f) ? 1u : 0u;
                    vst[i][j] = s ? 0.0f : v;
                    if (j < 4) p0 |= s << (8 * j); else p1 |= s << (8 * (j - 4));
                }
                uint2 pk; pk.x = p0; pk.y = p1;
                *reinterpret_cast<uint2*>((u8*)Yv + rowoff) = pk;
            } else if (MODE == 1) {
                float4 r0 = *reinterpret_cast<const float4*>(res + rowoff);
                float4 r1 = *reinterpret_cast<const float4*>(res + rowoff + 4);
                float rr[8] = {r0.x, r0.y, r0.z, r0.w, r1.x, r1.y, r1.z, r1.w};
                float o[8];
                #pragma unroll
                for (int j = 0; j < 8; ++j)
                    o[j] = acc[i][j] * scale[i] + shift[i] + rr[j];
                float4 s0 = {o[0], o[1], o[2], o[3]};
                float4 s1 = {o[4], o[5], o[6], o[7]};
                *reinterpret_cast<float4*>((float*)Yv + rowoff) = s0;
                *reinterpret_cast<float4*>((float*)Yv + rowoff + 4) = s1;
            } else {
                float* op = (float*)Yv + rowoff;
                float4 r0 = *reinterpret_cast<const float4*>(op);
                float4 r1 = *reinterpret_cast<const float4*>(op + 4);
                float rr[8] = {r0.x, r0.y, r0.z, r0.w, r1.x, r1.y, r1.z, r1.w};
                float o[8];
                #pragma unroll
                for (int j = 0; j < 8; ++j) {
                    const float y = acc[i][j] * scale[i] + shift[i];
                    float v = vst[i][j];
                    v += (y - v) * 0.5f;
                    const u32 s = (v >= 0.5f) ? 1u : 0u;
                    vst[i][j] = s ? 0.0f : v;
                    o[j] = rr[j] + (s ? 1.0f : 0.0f);
                }
                float4 s0 = {o[0], o[1], o[2], o[3]};
                float4 s1 = {o[4], o[5], o[6], o[7]};
                *reinterpret_cast<float4*>(op) = s0;
                *reinterpret_cast<float4*>(op + 4) = s1;
            }
        }
    }
}

// ---------------------------------------------------------------------------
// kv_raw[row=tb*C+c] = sum_n k*v  (exact integer; round-2 verbatim)
// ---------------------------------------------------------------------------
__global__ __launch_bounds__(256) void kv_reduce(const u8* __restrict__ ks,
                                                 const u8* __restrict__ vs,
                                                 float* __restrict__ kv)
{
    const int row = blockIdx.x * 4 + (threadIdx.x >> 6);  // [0, T*B*C)
    const int lane = threadIdx.x & 63;
    const u8* kp = ks + (size_t)row * N_SP;
    const u8* vp = vs + (size_t)row * N_SP;
    int acc = 0;
    #pragma unroll
    for (int n = 0; n < N_SP; n += 256) {
        uchar4 a = *reinterpret_cast<const uchar4*>(kp + n + lane * 4);
        uchar4 c = *reinterpret_cast<const uchar4*>(vp + n + lane * 4);
        acc += (a.x & c.x) + (a.y & c.y) + (a.z & c.z) + (a.w & c.w);
    }
    #pragma unroll
    for (int off = 32; off; off >>= 1) acc += __shfl_down(acc, off, 64);
    if (lane == 0) kv[row] = (float)acc;
}

// ---------------------------------------------------------------------------
// talking heads (8x8 over heads) + LIF -> kvs float {0,1}  (round-2 verbatim)
// ---------------------------------------------------------------------------
__global__ __launch_bounds__(256) void th_lif(const float* __restrict__ kvraw,
                                              const float* __restrict__ th,
                                              float* __restrict__ kvs)
{
    const int i = blockIdx.x * 256 + threadIdx.x;   // [0, B*C)
    const int b = i >> 9;
    const int c = i & 511;
    const int g = c >> 6;
    const int dd = c & 63;
    float v = 0.0f;
    #pragma unroll
    for (int t = 0; t < T_STEPS; ++t) {
        const float* base = kvraw + ((size_t)t * B_SZ + b) * C_IN;
        float x = 0.0f;
        #pragma unroll
        for (int hh = 0; hh < 8; ++hh)
            x += base[hh * 64 + dd] * th[g * 8 + hh];
        v += (x - v) * 0.5f;
        const float s = (v >= 0.5f) ? 1.0f : 0.0f;
        kvs[((size_t)t * B_SZ + b) * C_IN + c] = s;
        v = (s != 0.0f) ? 0.0f : v;
    }
}

extern "C" void kernel_launch(void* const* d_in, const int* in_sizes, int n_in,
                              void* d_out, int out_size, void* d_ws, size_t ws_size,
                              hipStream_t stream)
{
    const float* x       = (const float*)d_in[0];
    const float* q_w     = (const float*)d_in[1];
    const float* q_bn    = (const float*)d_in[2];
    const float* k_w     = (const float*)d_in[3];
    const float* k_bn    = (const float*)d_in[4];
    const float* v_w     = (const float*)d_in[5];
    const float* v_bn    = (const float*)d_in[6];
    const float* th_w    = (const float*)d_in[7];
    const float* proj_w  = (const float*)d_in[8];
    const float* proj_b  = (const float*)d_in[9];
    const float* proj_bn = (const float*)d_in[10];
    const float* fc1_w   = (const float*)d_in[11];
    const float* fc1_b   = (const float*)d_in[12];
    const float* fc1_bn  = (const float*)d_in[13];
    const float* fc2_w   = (const float*)d_in[14];
    const float* fc2_b   = (const float*)d_in[15];
    const float* fc2_bn  = (const float*)d_in[16];
    float* out = (float*)d_out;

    // workspace: round-2's proven 64 MiB + 128 KiB map
    u8* ws = (u8*)d_ws;
    const size_t SLOT = (size_t)T_STEPS * S_C;        // 16 MiB per u8 slot
    u8* xs = ws;                    // [TB][C][N] u8
    u8* qs = ws + SLOT;
    u8* ks = ws + 2 * SLOT;
    u8* vs = ws + 3 * SLOT;
    float* kvraw = (float*)(ws + 4 * SLOT);                 // [TB][C] f32 (64 KiB)
    float* kvsf  = kvraw + (size_t)T_STEPS * B_SZ * C_IN;   // [TB][C] f32 (64 KiB)
    u8* hdn = ws;                   // [TB][Ch][N] u8 = 64 MiB, reuses xs..vs (dead by fc1)

    // 1. xs = lif(x)
    lif_x_kernel<<<(int)(S_C / 256), 256, 0, stream>>>(x, xs);

    // 2. q/k/v = lif(bn(conv(xs)))  — fused triple GEMM
    mm<0, 0, false, 512, 512, true><<<dim3(8, 24, 8), 256, 0, stream>>>(
        q_w, k_w, v_w, xs, q_bn, k_bn, v_bn, nullptr, nullptr, nullptr, qs, ks, vs);

    // 3. kv_raw = rowwise dot(k, v); 4. talking heads + lif -> kvs (float 0/1)
    kv_reduce<<<(T_STEPS * B_SZ * C_IN) / 4, 256, 0, stream>>>(ks, vs, kvraw);
    th_lif<<<(B_SZ * C_IN) / 256, 256, 0, stream>>>(kvraw, th_w, kvsf);

    // 5. xout = bn(proj(q * kvs) + b) + x  -> d_out (f32)
    mm<1, 1, true, 512, 512, false><<<dim3(8, 8, 8), 256, 0, stream>>>(
        proj_w, nullptr, nullptr, qs, proj_bn, nullptr, nullptr, proj_b, kvsf, x,
        out, nullptr, nullptr);

    // 6. hdn = lif(bn(fc1(xout) + b))  -> u8 spikes in ws
    mm<0, 2, true, 512, 2048, false><<<dim3(8, 32, 8), 256, 0, stream>>>(
        fc1_w, nullptr, nullptr, out, fc1_bn, nullptr, nullptr, fc1_b, nullptr, nullptr,
        hdn, nullptr, nullptr);

    // 7. out = lif(bn(fc2(hdn) + b)) + xout   (in place on d_out)
    mm<2, 0, true, 2048, 512, false><<<dim3(8, 8, 8), 256, 0, stream>>>(
        fc2_w, nullptr, nullptr, hdn, fc2_bn, nullptr, nullptr, fc2_b, nullptr, nullptr,
        out, nullptr, nullptr);
}

// Round 7
// 3164.130 us; speedup vs baseline: 1.1046x; 1.1046x over previous
//
#include <hip/hip_runtime.h>

typedef unsigned char u8;
typedef unsigned int u32;

#define T_STEPS 4
#define B_SZ 8
#define C_IN 512
#define CH 2048
#define N_SP 1024
#define S_C ((size_t)B_SZ * C_IN * N_SP)    // elems per timestep

// ---------------------------------------------------------------------------
// lif_x: x [T,B,C,N] fp32 -> xs u8 spikes, same flat layout (round-2 verbatim).
// ---------------------------------------------------------------------------
__global__ __launch_bounds__(256) void lif_x_kernel(const float* __restrict__ in,
                                                    u8* __restrict__ out)
{
    size_t i = (size_t)blockIdx.x * 256 + threadIdx.x;
    float v = 0.0f;
    #pragma unroll
    for (int t = 0; t < T_STEPS; ++t) {
        float x = in[(size_t)t * S_C + i];
        v += (x - v) * 0.5f;
        u8 s = (v >= 0.5f) ? 1 : 0;
        out[(size_t)t * S_C + i] = s;
        v = s ? 0.0f : v;
    }
}

// ---------------------------------------------------------------------------
// Fused GEMM + BN (+bias) + LIF, fp32. Per-output math is ascending-k with a
// single fp32 accumulator -> bit-identical to the round-2/6 passing kernels.
// Layouts: X [TB][K][N], W [CO][K] fp32, Y [TB][CO][N].
// MODE 0: LIF -> u8 spikes. MODE 1: y + res -> f32. MODE 2: LIF spike + in-place res -> f32.
// BSRC 0: u8 X. BSRC 1: u8 X * kvsf[k] at staging (proj mask). BSRC 2: f32 X (fc1).
// Tile BM(=TM*16) co x 128 n, 256 threads, per-thread TM co x 8 n.
// Both operands staged in LDS (u8 unpacked to f32 at staging); register
// prefetch of the next k-tile overlaps global latency with FMA compute.
// Flat 1D grid; nblk = bid & 7 pins each n-slice to one XCD for L2 reuse.
// ---------------------------------------------------------------------------
template<int TM, int MODE, int BSRC, bool BIAS, int K, int CO, int NSEL>
__global__ __launch_bounds__(256) void mm(
    const float* __restrict__ W0, const float* __restrict__ W1, const float* __restrict__ W2,
    const void* __restrict__ Xv,
    const float* __restrict__ bn0, const float* __restrict__ bn1, const float* __restrict__ bn2,
    const float* __restrict__ bias,
    const float* __restrict__ kvsf,
    const float* __restrict__ res,
    void* Y0, void* Y1, void* Y2)
{
    constexpr int BM = TM * 16;
    constexpr int NB_CO = CO / BM;
    constexpr int KT = K / 16;
    constexpr int TPR = 256 / BM;     // threads per W row
    constexpr int KPT = 16 / TPR;     // k elems per staging thread

    __shared__ float As[16][BM + 8];  // [k][co]
    __shared__ float Xs[16][136];     // [k][n]

    const int bid = blockIdx.x;
    const int nblk = bid & 7;         // XCD-pinned n-slice
    int slot = bid >> 3;
    const int cb = slot % NB_CO; slot /= NB_CO;
    const int sel = (NSEL > 1) ? (slot % NSEL) : 0;
    const int b   = (NSEL > 1) ? (slot / NSEL) : slot;

    const float* W   = (NSEL == 1 || sel == 0) ? W0  : (sel == 1 ? W1  : W2);
    const float* bnp = (NSEL == 1 || sel == 0) ? bn0 : (sel == 1 ? bn1 : bn2);
    void* Yv         = (NSEL == 1 || sel == 0) ? Y0  : (sel == 1 ? Y1  : Y2);

    const int coBase = cb * BM;
    const int n0blk = nblk * 128;
    const int tid = threadIdx.x;
    const int tx = tid & 15, ty = tid >> 4;
    const int n0 = n0blk + tx * 8;

    // staging indices
    const int wr = tid / TPR;                // W row (co)
    const int wk = (tid % TPR) * KPT;        // W k-seg
    const int xk = tid >> 4;                 // X row (k)
    const int xn = (tid & 15) * 8;           // X n-seg

    // BN constants (round-2 expressions)
    float scale[TM], shift[TM];
    #pragma unroll
    for (int i = 0; i < TM; ++i) {
        const int co = coBase + ty * TM + i;
        const float g = bnp[co], be = bnp[CO + co];
        const float mn = bnp[2 * CO + co], vr = bnp[3 * CO + co];
        scale[i] = g / sqrtf(vr + 1e-5f);
        shift[i] = be - mn * scale[i];
        if (BIAS) shift[i] += bias[co] * scale[i];
    }

    float vst[TM][8];
    if (MODE != 1) {
        #pragma unroll
        for (int i = 0; i < TM; ++i)
            #pragma unroll
            for (int j = 0; j < 8; ++j) vst[i][j] = 0.0f;
    }

    for (int t = 0; t < T_STEPS; ++t) {
        const int tb = t * B_SZ + b;
        const u8* Xu = (const u8*)Xv + (size_t)tb * K * N_SP;
        const float* Xf = (const float*)Xv + (size_t)tb * K * N_SP;

        float acc[TM][8];
        #pragma unroll
        for (int i = 0; i < TM; ++i)
            #pragma unroll
            for (int j = 0; j < 8; ++j) acc[i][j] = 0.0f;

        float wreg[KPT];
        uint2 xu;
        float mreg = 1.0f;
        float xreg[8];

        auto prefetch = [&](int kt) {
            const float* wp = W + (size_t)(coBase + wr) * K + kt * 16 + wk;
            *reinterpret_cast<float4*>(&wreg[0]) = *reinterpret_cast<const float4*>(wp);
            if constexpr (KPT == 8)
                *reinterpret_cast<float4*>(&wreg[4]) = *reinterpret_cast<const float4*>(wp + 4);
            if constexpr (BSRC <= 1) {
                xu = *reinterpret_cast<const uint2*>(
                    Xu + (size_t)(kt * 16 + xk) * N_SP + n0blk + xn);
                if constexpr (BSRC == 1)
                    mreg = kvsf[(size_t)tb * K + kt * 16 + xk];
            } else {
                const float* xp = Xf + (size_t)(kt * 16 + xk) * N_SP + n0blk + xn;
                *reinterpret_cast<float4*>(&xreg[0]) = *reinterpret_cast<const float4*>(xp);
                *reinterpret_cast<float4*>(&xreg[4]) = *reinterpret_cast<const float4*>(xp + 4);
            }
        };

        prefetch(0);

        for (int kt = 0; kt < KT; ++kt) {
            __syncthreads();    // previous tile's compute done; LDS reusable
            // write prefetched regs to LDS
            #pragma unroll
            for (int j = 0; j < KPT; ++j) As[wk + j][wr] = wreg[j];
            if constexpr (BSRC <= 1) {
                float xf[8];
                xf[0] = (float)( xu.x        & 0xFFu);
                xf[1] = (float)((xu.x >> 8 ) & 0xFFu);
                xf[2] = (float)((xu.x >> 16) & 0xFFu);
                xf[3] = (float)( xu.x >> 24        );
                xf[4] = (float)( xu.y        & 0xFFu);
                xf[5] = (float)((xu.y >> 8 ) & 0xFFu);
                xf[6] = (float)((xu.y >> 16) & 0xFFu);
                xf[7] = (float)( xu.y >> 24        );
                if constexpr (BSRC == 1) {
                    #pragma unroll
                    for (int j = 0; j < 8; ++j) xf[j] *= mreg;   // 0/1 x 0/1: exact
                }
                float4 s0 = {xf[0], xf[1], xf[2], xf[3]};
                float4 s1 = {xf[4], xf[5], xf[6], xf[7]};
                *reinterpret_cast<float4*>(&Xs[xk][xn]) = s0;
                *reinterpret_cast<float4*>(&Xs[xk][xn + 4]) = s1;
            } else {
                *reinterpret_cast<float4*>(&Xs[xk][xn]) =
                    *reinterpret_cast<const float4*>(&xreg[0]);
                *reinterpret_cast<float4*>(&Xs[xk][xn + 4]) =
                    *reinterpret_cast<const float4*>(&xreg[4]);
            }
            __syncthreads();
            if (kt + 1 < KT) prefetch(kt + 1);   // overlaps with compute below

            #pragma unroll
            for (int kk = 0; kk < 16; ++kk) {
                float a[TM], xw[8];
                *reinterpret_cast<float4*>(&a[0]) =
                    *reinterpret_cast<const float4*>(&As[kk][ty * TM]);
                if constexpr (TM == 8)
                    *reinterpret_cast<float4*>(&a[4]) =
                        *reinterpret_cast<const float4*>(&As[kk][ty * TM + 4]);
                *reinterpret_cast<float4*>(&xw[0]) =
                    *reinterpret_cast<const float4*>(&Xs[kk][tx * 8]);
                *reinterpret_cast<float4*>(&xw[4]) =
                    *reinterpret_cast<const float4*>(&Xs[kk][tx * 8 + 4]);
                #pragma unroll
                for (int i = 0; i < TM; ++i)
                    #pragma unroll
                    for (int j = 0; j < 8; ++j)
                        acc[i][j] += a[i] * xw[j];   // ascending-k, single acc
            }
        }

        // epilogue for this timestep (round-2/6 expressions, bit-identical)
        #pragma unroll
        for (int i = 0; i < TM; ++i) {
            const int co = coBase + ty * TM + i;
            const size_t rowoff = ((size_t)tb * CO + co) * N_SP + n0;
            if constexpr (MODE == 0) {
                u32 p0 = 0, p1 = 0;
                #pragma unroll
                for (int j = 0; j < 8; ++j) {
                    const float y = acc[i][j] * scale[i] + shift[i];
                    float v = vst[i][j];
                    v += (y - v) * 0.5f;
                    const u32 s = (v >= 0.5f) ? 1u : 0u;
                    vst[i][j] = s ? 0.0f : v;
                    if (j < 4) p0 |= s << (8 * j); else p1 |= s << (8 * (j - 4));
                }
                uint2 pk; pk.x = p0; pk.y = p1;
                *reinterpret_cast<uint2*>((u8*)Yv + rowoff) = pk;
            } else if constexpr (MODE == 1) {
                float4 r0 = *reinterpret_cast<const float4*>(res + rowoff);
                float4 r1 = *reinterpret_cast<const float4*>(res + rowoff + 4);
                float rr[8] = {r0.x, r0.y, r0.z, r0.w, r1.x, r1.y, r1.z, r1.w};
                float o[8];
                #pragma unroll
                for (int j = 0; j < 8; ++j)
                    o[j] = acc[i][j] * scale[i] + shift[i] + rr[j];
                float4 s0 = {o[0], o[1], o[2], o[3]};
                float4 s1 = {o[4], o[5], o[6], o[7]};
                *reinterpret_cast<float4*>((float*)Yv + rowoff) = s0;
                *reinterpret_cast<float4*>((float*)Yv + rowoff + 4) = s1;
            } else {
                float* op = (float*)Yv + rowoff;
                float4 r0 = *reinterpret_cast<const float4*>(op);
                float4 r1 = *reinterpret_cast<const float4*>(op + 4);
                float rr[8] = {r0.x, r0.y, r0.z, r0.w, r1.x, r1.y, r1.z, r1.w};
                float o[8];
                #pragma unroll
                for (int j = 0; j < 8; ++j) {
                    const float y = acc[i][j] * scale[i] + shift[i];
                    float v = vst[i][j];
                    v += (y - v) * 0.5f;
                    const u32 s = (v >= 0.5f) ? 1u : 0u;
                    vst[i][j] = s ? 0.0f : v;
                    o[j] = rr[j] + (s ? 1.0f : 0.0f);
                }
                float4 s0 = {o[0], o[1], o[2], o[3]};
                float4 s1 = {o[4], o[5], o[6], o[7]};
                *reinterpret_cast<float4*>(op) = s0;
                *reinterpret_cast<float4*>(op + 4) = s1;
            }
        }
    }
}

// ---------------------------------------------------------------------------
// kv_raw[row=tb*C+c] = sum_n k*v  (exact integer; round-2 verbatim)
// ---------------------------------------------------------------------------
__global__ __launch_bounds__(256) void kv_reduce(const u8* __restrict__ ks,
                                                 const u8* __restrict__ vs,
                                                 float* __restrict__ kv)
{
    const int row = blockIdx.x * 4 + (threadIdx.x >> 6);  // [0, T*B*C)
    const int lane = threadIdx.x & 63;
    const u8* kp = ks + (size_t)row * N_SP;
    const u8* vp = vs + (size_t)row * N_SP;
    int acc = 0;
    #pragma unroll
    for (int n = 0; n < N_SP; n += 256) {
        uchar4 a = *reinterpret_cast<const uchar4*>(kp + n + lane * 4);
        uchar4 c = *reinterpret_cast<const uchar4*>(vp + n + lane * 4);
        acc += (a.x & c.x) + (a.y & c.y) + (a.z & c.z) + (a.w & c.w);
    }
    #pragma unroll
    for (int off = 32; off; off >>= 1) acc += __shfl_down(acc, off, 64);
    if (lane == 0) kv[row] = (float)acc;
}

// ---------------------------------------------------------------------------
// talking heads (8x8 over heads) + LIF -> kvs float {0,1}  (round-2 verbatim)
// ---------------------------------------------------------------------------
__global__ __launch_bounds__(256) void th_lif(const float* __restrict__ kvraw,
                                              const float* __restrict__ th,
                                              float* __restrict__ kvs)
{
    const int i = blockIdx.x * 256 + threadIdx.x;   // [0, B*C)
    const int b = i >> 9;
    const int c = i & 511;
    const int g = c >> 6;
    const int dd = c & 63;
    float v = 0.0f;
    #pragma unroll
    for (int t = 0; t < T_STEPS; ++t) {
        const float* base = kvraw + ((size_t)t * B_SZ + b) * C_IN;
        float x = 0.0f;
        #pragma unroll
        for (int hh = 0; hh < 8; ++hh)
            x += base[hh * 64 + dd] * th[g * 8 + hh];
        v += (x - v) * 0.5f;
        const float s = (v >= 0.5f) ? 1.0f : 0.0f;
        kvs[((size_t)t * B_SZ + b) * C_IN + c] = s;
        v = (s != 0.0f) ? 0.0f : v;
    }
}

extern "C" void kernel_launch(void* const* d_in, const int* in_sizes, int n_in,
                              void* d_out, int out_size, void* d_ws, size_t ws_size,
                              hipStream_t stream)
{
    const float* x       = (const float*)d_in[0];
    const float* q_w     = (const float*)d_in[1];
    const float* q_bn    = (const float*)d_in[2];
    const float* k_w     = (const float*)d_in[3];
    const float* k_bn    = (const float*)d_in[4];
    const float* v_w     = (const float*)d_in[5];
    const float* v_bn    = (const float*)d_in[6];
    const float* th_w    = (const float*)d_in[7];
    const float* proj_w  = (const float*)d_in[8];
    const float* proj_b  = (const float*)d_in[9];
    const float* proj_bn = (const float*)d_in[10];
    const float* fc1_w   = (const float*)d_in[11];
    const float* fc1_b   = (const float*)d_in[12];
    const float* fc1_bn  = (const float*)d_in[13];
    const float* fc2_w   = (const float*)d_in[14];
    const float* fc2_b   = (const float*)d_in[15];
    const float* fc2_bn  = (const float*)d_in[16];
    float* out = (float*)d_out;

    // workspace: round-2/6's proven 64 MiB + 128 KiB map
    u8* ws = (u8*)d_ws;
    const size_t SLOT = (size_t)T_STEPS * S_C;        // 16 MiB per u8 slot
    u8* xs = ws;                    // [TB][C][N] u8
    u8* qs = ws + SLOT;
    u8* ks = ws + 2 * SLOT;
    u8* vs = ws + 3 * SLOT;
    float* kvraw = (float*)(ws + 4 * SLOT);                 // [TB][C] f32 (64 KiB)
    float* kvsf  = kvraw + (size_t)T_STEPS * B_SZ * C_IN;   // [TB][C] f32 (64 KiB)
    u8* hdn = ws;                   // [TB][Ch][N] u8 = 64 MiB, reuses xs..vs (dead by fc1)

    // 1. xs = lif(x)
    lif_x_kernel<<<(int)(S_C / 256), 256, 0, stream>>>(x, xs);

    // 2. q/k/v = lif(bn(conv(xs)))  — fused triple GEMM
    //    grid = 8 n-slices * (4 co * 3 sel * 8 b) = 768
    mm<8, 0, 0, false, 512, 512, 3><<<768, 256, 0, stream>>>(
        q_w, k_w, v_w, xs, q_bn, k_bn, v_bn, nullptr, nullptr, nullptr, qs, ks, vs);

    // 3. kv_raw = rowwise dot(k, v); 4. talking heads + lif -> kvs (float 0/1)
    kv_reduce<<<(T_STEPS * B_SZ * C_IN) / 4, 256, 0, stream>>>(ks, vs, kvraw);
    th_lif<<<(B_SZ * C_IN) / 256, 256, 0, stream>>>(kvraw, th_w, kvsf);

    // 5. xout = bn(proj(q * kvs) + b) + x  -> d_out (f32);  grid 8*(4*8)=256
    mm<8, 1, 1, true, 512, 512, 1><<<256, 256, 0, stream>>>(
        proj_w, nullptr, nullptr, qs, proj_bn, nullptr, nullptr, proj_b, kvsf, x,
        out, nullptr, nullptr);

    // 6. hdn = lif(bn(fc1(xout) + b))  -> u8 spikes in ws;  grid 8*(16*8)=1024
    mm<8, 0, 2, true, 512, 2048, 1><<<1024, 256, 0, stream>>>(
        fc1_w, nullptr, nullptr, out, fc1_bn, nullptr, nullptr, fc1_b, nullptr, nullptr,
        hdn, nullptr, nullptr);

    // 7. out = lif(bn(fc2(hdn) + b)) + xout  (in place on d_out);  grid 256
    mm<8, 2, 0, true, 2048, 512, 1><<<256, 256, 0, stream>>>(
        fc2_w, nullptr, nullptr, hdn, fc2_bn, nullptr, nullptr, fc2_b, nullptr, nullptr,
        out, nullptr, nullptr);
}